// Round 1
// baseline (209.953 us; speedup 1.0000x reference)
//
#include <hip/hip_runtime.h>
#include <hip/hip_bf16.h>

typedef _Float16 f16x8 __attribute__((ext_vector_type(8)));
typedef _Float16 f16x4 __attribute__((ext_vector_type(4)));
typedef float f32x4 __attribute__((ext_vector_type(4)));

#define MFMA16(a, b, c) __builtin_amdgcn_mfma_f32_16x16x32_f16((a), (b), (c), 0, 0, 0)

// load 8 consecutive fp32 and split each into fp16 hi + fp16 lo
__device__ __forceinline__ void load_split8(const float* __restrict__ p, f16x8& hi, f16x8& lo) {
  const float4 a = *reinterpret_cast<const float4*>(p);
  const float4 b = *reinterpret_cast<const float4*>(p + 4);
  float v[8] = {a.x, a.y, a.z, a.w, b.x, b.y, b.z, b.w};
#pragma unroll
  for (int e = 0; e < 8; ++e) {
    _Float16 h = (_Float16)v[e];
    hi[e] = h;
    lo[e] = (_Float16)(v[e] - (float)h);
  }
}

// ---------------- kernel 0: W transpose + fp16 hi/lo split -----------------
// Wq/Wk/Wv are [384][64] row-major (C,H). Output WT[n][c], n in [0,192), c in [0,384).
__global__ __launch_bounds__(256) void wprep_kernel(
    const float* __restrict__ Wq, const float* __restrict__ Wk, const float* __restrict__ Wv,
    _Float16* __restrict__ wt_hi, _Float16* __restrict__ wt_lo) {
  int i = blockIdx.x * 256 + threadIdx.x;
  if (i >= 192 * 384) return;
  int n = i / 384, c = i - n * 384;
  int sel = n >> 6, h = n & 63;
  const float* W = (sel == 0) ? Wq : (sel == 1) ? Wk : Wv;
  float val = W[c * 64 + h];
  _Float16 hi = (_Float16)val;
  wt_hi[i] = hi;
  wt_lo[i] = (_Float16)(val - (float)hi);
}

// ---------------- kernel 1: QKV projection GEMM ----------------------------
// x [131072][384] fp32 @ WT^T -> q,k,v [131072][64] fp32.
// Block: 256 thr (4 waves), M-tile 64, N full 192. Wave w owns cols [48w,48w+48).
__global__ __launch_bounds__(256) void qkv_gemm_kernel(
    const float* __restrict__ x,
    const _Float16* __restrict__ wt_hi, const _Float16* __restrict__ wt_lo,
    float* __restrict__ q, float* __restrict__ k, float* __restrict__ v) {
  __shared__ __align__(16) _Float16 xhi[64 * 40];
  __shared__ __align__(16) _Float16 xlo[64 * 40];
  const int tid = threadIdx.x;
  const int wave = tid >> 6, lane = tid & 63;
  const int g = lane >> 4, l16 = lane & 15;
  const int row0 = blockIdx.x * 64;

  f32x4 acc[4][3] = {};

  for (int kk = 0; kk < 384; kk += 32) {
    if (kk) __syncthreads();
    // stage x[64][32] -> LDS fp16 hi/lo (stride 40 to dodge bank conflicts)
#pragma unroll
    for (int it = 0; it < 2; ++it) {
      int fi = tid + it * 256;         // 512 float4 = 64 rows x 8 quads
      int r = fi >> 3;
      int c = (fi & 7) << 2;
      const float4 xv = *reinterpret_cast<const float4*>(&x[(size_t)(row0 + r) * 384 + kk + c]);
      float vv[4] = {xv.x, xv.y, xv.z, xv.w};
      f16x4 hi, lo;
#pragma unroll
      for (int e = 0; e < 4; ++e) {
        _Float16 h = (_Float16)vv[e];
        hi[e] = h;
        lo[e] = (_Float16)(vv[e] - (float)h);
      }
      *reinterpret_cast<f16x4*>(&xhi[r * 40 + c]) = hi;
      *reinterpret_cast<f16x4*>(&xlo[r * 40 + c]) = lo;
    }
    __syncthreads();

    f16x8 ahi[4], alo[4];
#pragma unroll
    for (int rt = 0; rt < 4; ++rt) {
      int off = (rt * 16 + l16) * 40 + g * 8;
      ahi[rt] = *reinterpret_cast<const f16x8*>(&xhi[off]);
      alo[rt] = *reinterpret_cast<const f16x8*>(&xlo[off]);
    }
    f16x8 bhi[3], blo[3];
#pragma unroll
    for (int ct = 0; ct < 3; ++ct) {
      int n = wave * 48 + ct * 16 + l16;
      size_t o = (size_t)n * 384 + kk + g * 8;
      bhi[ct] = *reinterpret_cast<const f16x8*>(&wt_hi[o]);
      blo[ct] = *reinterpret_cast<const f16x8*>(&wt_lo[o]);
    }
#pragma unroll
    for (int rt = 0; rt < 4; ++rt)
#pragma unroll
      for (int ct = 0; ct < 3; ++ct) {
        acc[rt][ct] = MFMA16(ahi[rt], bhi[ct], acc[rt][ct]);
        acc[rt][ct] = MFMA16(alo[rt], bhi[ct], acc[rt][ct]);
        acc[rt][ct] = MFMA16(ahi[rt], blo[ct], acc[rt][ct]);
      }
  }

  // epilogue: D row=(lane>>4)*4+j, col=lane&15
#pragma unroll
  for (int rt = 0; rt < 4; ++rt)
#pragma unroll
    for (int ct = 0; ct < 3; ++ct) {
      int n = wave * 48 + ct * 16 + l16;
      int sel = n >> 6, h = n & 63;
      float* dst = (sel == 0) ? q : (sel == 1) ? k : v;
#pragma unroll
      for (int j = 0; j < 4; ++j) {
        int m = row0 + rt * 16 + g * 4 + j;
        dst[(size_t)m * 64 + h] = acc[rt][ct][j];
      }
    }
}

// ---------------- kernel 2: causal attention per (batch, 32-row q-block) ---
// grid (8, 512): blockIdx.x = q-row block, blockIdx.y = batch. 256 thr, 4 waves.
__global__ __launch_bounds__(256) void attn_kernel(
    const float* __restrict__ q, const float* __restrict__ k, const float* __restrict__ v,
    float* __restrict__ out) {
  __shared__ __align__(16) float S[32 * 264];
  __shared__ __align__(16) _Float16 P[32 * 264];
  __shared__ float lsum[32];

  const int b = blockIdx.y, rb = blockIdx.x;
  const int r0 = rb * 32;
  const int tid = threadIdx.x;
  const int wave = tid >> 6, lane = tid & 63;
  const int g = lane >> 4, l16 = lane & 15;
  const size_t base = (size_t)b * 256 * 64;
  const float scale = 19.595917942265423f;  // sqrt(384)

  // ---- QK^T: wave w computes S cols [64w, 64w+64), rows [r0, r0+32) ----
  f32x4 acc[2][4] = {};
#pragma unroll
  for (int ks = 0; ks < 2; ++ks) {
    int kk = ks * 32;
    f16x8 ahi[2], alo[2];
#pragma unroll
    for (int rt = 0; rt < 2; ++rt) {
      int t = r0 + rt * 16 + l16;
      load_split8(&q[base + (size_t)t * 64 + kk + g * 8], ahi[rt], alo[rt]);
    }
    f16x8 bhi[4], blo[4];
#pragma unroll
    for (int ct = 0; ct < 4; ++ct) {
      int s = wave * 64 + ct * 16 + l16;
      load_split8(&k[base + (size_t)s * 64 + kk + g * 8], bhi[ct], blo[ct]);
    }
#pragma unroll
    for (int rt = 0; rt < 2; ++rt)
#pragma unroll
      for (int ct = 0; ct < 4; ++ct) {
        acc[rt][ct] = MFMA16(ahi[rt], bhi[ct], acc[rt][ct]);
        acc[rt][ct] = MFMA16(alo[rt], bhi[ct], acc[rt][ct]);
        acc[rt][ct] = MFMA16(ahi[rt], blo[ct], acc[rt][ct]);
      }
  }
  // write scaled+masked S to LDS
#pragma unroll
  for (int rt = 0; rt < 2; ++rt)
#pragma unroll
    for (int ct = 0; ct < 4; ++ct)
#pragma unroll
      for (int j = 0; j < 4; ++j) {
        int tl = rt * 16 + g * 4 + j;          // local row
        int s = wave * 64 + ct * 16 + l16;     // global col
        float val = acc[rt][ct][j] * scale;
        if (s > r0 + tl) val = -1e30f;         // causal mask
        S[tl * 264 + s] = val;
      }
  __syncthreads();

  // ---- softmax: 8 threads per row, 32 cols each ----
  {
    int row = tid >> 3, sub = tid & 7;
    float vals[32];
    float m = -3.0e38f;
#pragma unroll
    for (int i = 0; i < 32; ++i) {
      vals[i] = S[row * 264 + sub * 32 + i];
      m = fmaxf(m, vals[i]);
    }
    m = fmaxf(m, __shfl_xor(m, 1));
    m = fmaxf(m, __shfl_xor(m, 2));
    m = fmaxf(m, __shfl_xor(m, 4));
    float sum = 0.f;
#pragma unroll
    for (int i = 0; i < 32; ++i) {
      float p = __expf(vals[i] - m);
      sum += p;
      P[row * 264 + sub * 32 + i] = (_Float16)p;
    }
    sum += __shfl_xor(sum, 1);
    sum += __shfl_xor(sum, 2);
    sum += __shfl_xor(sum, 4);
    if (sub == 0) lsum[row] = sum;
  }
  __syncthreads();

  // ---- PV: out[32][64] = P[32][256] @ v[256][64]; wave w -> cols [16w,16w+16) ----
  f32x4 o[2] = {};
  const int h = wave * 16 + l16;
#pragma unroll
  for (int ks = 0; ks < 8; ++ks) {
    int kk = ks * 32;
    f16x8 a0 = *reinterpret_cast<const f16x8*>(&P[(0 * 16 + l16) * 264 + kk + g * 8]);
    f16x8 a1 = *reinterpret_cast<const f16x8*>(&P[(1 * 16 + l16) * 264 + kk + g * 8]);
    f16x8 bf;
#pragma unroll
    for (int e = 0; e < 8; ++e)
      bf[e] = (_Float16)v[base + (size_t)(kk + g * 8 + e) * 64 + h];
    o[0] = MFMA16(a0, bf, o[0]);
    o[1] = MFMA16(a1, bf, o[1]);
  }
#pragma unroll
  for (int rt = 0; rt < 2; ++rt)
#pragma unroll
    for (int j = 0; j < 4; ++j) {
      int tl = rt * 16 + g * 4 + j;
      float inv = 1.0f / lsum[tl];
      out[base + (size_t)(r0 + tl) * 64 + h] = o[rt][j] * inv;
    }
}

// ---------------------------------------------------------------------------
extern "C" void kernel_launch(void* const* d_in, const int* in_sizes, int n_in,
                              void* d_out, int out_size, void* d_ws, size_t ws_size,
                              hipStream_t stream) {
  const float* x  = (const float*)d_in[0];
  const float* Wq = (const float*)d_in[1];
  const float* Wk = (const float*)d_in[2];
  const float* Wv = (const float*)d_in[3];

  char* ws = (char*)d_ws;
  _Float16* wt_hi = (_Float16*)ws;                         // 192*384 fp16
  _Float16* wt_lo = (_Float16*)(ws + 294912);              // 192*384 fp16
  float* q = (float*)(ws + 1048576);                       // 131072*64 fp32
  float* k = q + (size_t)131072 * 64;
  float* v = k + (size_t)131072 * 64;

  wprep_kernel<<<288, 256, 0, stream>>>(Wq, Wk, Wv, wt_hi, wt_lo);
  qkv_gemm_kernel<<<2048, 256, 0, stream>>>(x, wt_hi, wt_lo, q, k, v);
  attn_kernel<<<dim3(8, 512), 256, 0, stream>>>(q, k, v, (float*)d_out);
}

// Round 2
// 205.420 us; speedup vs baseline: 1.0221x; 1.0221x over previous
//
#include <hip/hip_runtime.h>
#include <hip/hip_bf16.h>

typedef _Float16 f16x8 __attribute__((ext_vector_type(8)));
typedef _Float16 f16x4 __attribute__((ext_vector_type(4)));
typedef float f32x4 __attribute__((ext_vector_type(4)));

#define MFMA16(a, b, c) __builtin_amdgcn_mfma_f32_16x16x32_f16((a), (b), (c), 0, 0, 0)

// ---------------- kernel 0: W transpose + fp16 hi/lo split -----------------
// Wq/Wk/Wv are [384][64] row-major (C,H). Output WT[n][c], n in [0,192), c in [0,384).
__global__ __launch_bounds__(256) void wprep_kernel(
    const float* __restrict__ Wq, const float* __restrict__ Wk, const float* __restrict__ Wv,
    _Float16* __restrict__ wt_hi, _Float16* __restrict__ wt_lo) {
  int i = blockIdx.x * 256 + threadIdx.x;
  if (i >= 192 * 384) return;
  int n = i / 384, c = i - n * 384;
  int sel = n >> 6, h = n & 63;
  const float* W = (sel == 0) ? Wq : (sel == 1) ? Wk : Wv;
  float val = W[c * 64 + h];
  _Float16 hi = (_Float16)val;
  wt_hi[i] = hi;
  wt_lo[i] = (_Float16)(val - (float)hi);
}

// ---------------- kernel 1: QKV projection GEMM ----------------------------
// x [131072][384] fp32 -> qhi/qlo/khi/klo [131072][64] f16, vT [512][64][256] f16.
// Block: 256 thr (4 waves), M-tile 64. Wave w owns col h = 16w+l16 of EACH of q,k,v.
// BK=64, double-buffered LDS, loads for tile t+1 issued before barrier of tile t.
__global__ __launch_bounds__(256) void qkv_gemm_kernel(
    const float* __restrict__ x,
    const _Float16* __restrict__ wt_hi, const _Float16* __restrict__ wt_lo,
    _Float16* __restrict__ qhi, _Float16* __restrict__ qlo,
    _Float16* __restrict__ khi, _Float16* __restrict__ klo,
    _Float16* __restrict__ vT) {
  __shared__ __align__(16) _Float16 xh[2][64 * 72];
  __shared__ __align__(16) _Float16 xl[2][64 * 72];
  const int tid = threadIdx.x;
  const int wave = tid >> 6, lane = tid & 63;
  const int g = lane >> 4, l16 = lane & 15;
  const int row0 = blockIdx.x * 64;
  const int sr = tid >> 4, sc = tid & 15;  // staging: row-sub, float4-quad

  f32x4 acc[4][3] = {};
  float4 cur[4], nxt[4];

#pragma unroll
  for (int it = 0; it < 4; ++it)
    cur[it] = *reinterpret_cast<const float4*>(&x[(size_t)(row0 + 16 * it + sr) * 384 + sc * 4]);

#pragma unroll
  for (int t = 0; t < 6; ++t) {
    _Float16* bh = xh[t & 1];
    _Float16* bl = xl[t & 1];
    // convert + write tile t into LDS
#pragma unroll
    for (int it = 0; it < 4; ++it) {
      float vv[4] = {cur[it].x, cur[it].y, cur[it].z, cur[it].w};
      f16x4 hi4, lo4;
#pragma unroll
      for (int e = 0; e < 4; ++e) {
        _Float16 h = (_Float16)vv[e];
        hi4[e] = h;
        lo4[e] = (_Float16)(vv[e] - (float)h);
      }
      int off = (16 * it + sr) * 72 + sc * 4;
      *reinterpret_cast<f16x4*>(&bh[off]) = hi4;
      *reinterpret_cast<f16x4*>(&bl[off]) = lo4;
    }
    // issue next tile's global loads (latency hides under barrier + compute)
    if (t < 5) {
#pragma unroll
      for (int it = 0; it < 4; ++it)
        nxt[it] = *reinterpret_cast<const float4*>(
            &x[(size_t)(row0 + 16 * it + sr) * 384 + (t + 1) * 64 + sc * 4]);
    }
    __syncthreads();
    // compute tile t
#pragma unroll
    for (int ks = 0; ks < 2; ++ks) {
      const int ko = ks * 32 + g * 8;
      f16x8 bqh, bql, bkh, bkl, bvh;
      {
        size_t o0 = (size_t)(0 * 64 + wave * 16 + l16) * 384 + t * 64 + ko;
        size_t o1 = (size_t)(1 * 64 + wave * 16 + l16) * 384 + t * 64 + ko;
        size_t o2 = (size_t)(2 * 64 + wave * 16 + l16) * 384 + t * 64 + ko;
        bqh = *reinterpret_cast<const f16x8*>(&wt_hi[o0]);
        bql = *reinterpret_cast<const f16x8*>(&wt_lo[o0]);
        bkh = *reinterpret_cast<const f16x8*>(&wt_hi[o1]);
        bkl = *reinterpret_cast<const f16x8*>(&wt_lo[o1]);
        bvh = *reinterpret_cast<const f16x8*>(&wt_hi[o2]);
      }
#pragma unroll
      for (int rt = 0; rt < 4; ++rt) {
        int ao = (rt * 16 + l16) * 72 + ko;
        f16x8 ah = *reinterpret_cast<const f16x8*>(&bh[ao]);
        f16x8 al = *reinterpret_cast<const f16x8*>(&bl[ao]);
        acc[rt][0] = MFMA16(ah, bqh, acc[rt][0]);
        acc[rt][0] = MFMA16(al, bqh, acc[rt][0]);
        acc[rt][0] = MFMA16(ah, bql, acc[rt][0]);
        acc[rt][1] = MFMA16(ah, bkh, acc[rt][1]);
        acc[rt][1] = MFMA16(al, bkh, acc[rt][1]);
        acc[rt][1] = MFMA16(ah, bkl, acc[rt][1]);
        acc[rt][2] = MFMA16(ah, bvh, acc[rt][2]);  // v: single pass
      }
    }
    if (t < 5) {
#pragma unroll
      for (int it = 0; it < 4; ++it) cur[it] = nxt[it];
    }
  }

  // epilogue: D row=(lane>>4)*4+j (within 16-tile), col=l16
  const int hcol = wave * 16 + l16;
  const int bidx = row0 >> 8;
  const int s0base = row0 & 255;
#pragma unroll
  for (int rt = 0; rt < 4; ++rt) {
#pragma unroll
    for (int j = 0; j < 4; ++j) {
      size_t m = (size_t)(row0 + rt * 16 + g * 4 + j);
      float qv = acc[rt][0][j];
      _Float16 qh = (_Float16)qv;
      qhi[m * 64 + hcol] = qh;
      qlo[m * 64 + hcol] = (_Float16)(qv - (float)qh);
      float kv = acc[rt][1][j];
      _Float16 kh = (_Float16)kv;
      khi[m * 64 + hcol] = kh;
      klo[m * 64 + hcol] = (_Float16)(kv - (float)kh);
    }
    f16x4 vh;
#pragma unroll
    for (int j = 0; j < 4; ++j) vh[j] = (_Float16)acc[rt][2][j];
    *reinterpret_cast<f16x4*>(
        &vT[(size_t)bidx * 16384 + (size_t)hcol * 256 + s0base + rt * 16 + g * 4]) = vh;
  }
}

// ---------------- kernel 2: causal attention per (batch, 32-row q-block) ---
// grid (8, 512). 256 thr, 4 waves. Causal skip: only cols < r0+32 are touched.
__global__ __launch_bounds__(256) void attn_kernel(
    const _Float16* __restrict__ qhi, const _Float16* __restrict__ qlo,
    const _Float16* __restrict__ khi, const _Float16* __restrict__ klo,
    const _Float16* __restrict__ vT, float* __restrict__ out) {
  __shared__ __align__(16) float S[32 * 264];
  __shared__ __align__(16) _Float16 P[32 * 264];
  __shared__ float lsum[32];

  const int b = blockIdx.y, rb = blockIdx.x;
  const int r0 = rb * 32;
  const int ncol = r0 + 32;  // needed score columns
  const int tid = threadIdx.x;
  const int wave = tid >> 6, lane = tid & 63;
  const int g = lane >> 4, l16 = lane & 15;
  const size_t rowbase = (size_t)b * 256;
  const float scale = 19.595917942265423f;  // sqrt(384)

  // ---- QK^T (3-pass split fp16) ----
  f32x4 acc[2][4] = {};
  if (wave * 64 < ncol) {
#pragma unroll
    for (int ks = 0; ks < 2; ++ks) {
      const int ko = ks * 32 + g * 8;
      f16x8 ah[2], al[2];
#pragma unroll
      for (int rt = 0; rt < 2; ++rt) {
        size_t o = (rowbase + r0 + rt * 16 + l16) * 64 + ko;
        ah[rt] = *reinterpret_cast<const f16x8*>(&qhi[o]);
        al[rt] = *reinterpret_cast<const f16x8*>(&qlo[o]);
      }
#pragma unroll
      for (int ct = 0; ct < 4; ++ct) {
        if (wave * 64 + ct * 16 < ncol) {
          size_t o = (rowbase + wave * 64 + ct * 16 + l16) * 64 + ko;
          f16x8 bh = *reinterpret_cast<const f16x8*>(&khi[o]);
          f16x8 bl = *reinterpret_cast<const f16x8*>(&klo[o]);
#pragma unroll
          for (int rt = 0; rt < 2; ++rt) {
            acc[rt][ct] = MFMA16(ah[rt], bh, acc[rt][ct]);
            acc[rt][ct] = MFMA16(al[rt], bh, acc[rt][ct]);
            acc[rt][ct] = MFMA16(ah[rt], bl, acc[rt][ct]);
          }
        }
      }
    }
#pragma unroll
    for (int ct = 0; ct < 4; ++ct) {
      if (wave * 64 + ct * 16 < ncol) {
        int s = wave * 64 + ct * 16 + l16;
#pragma unroll
        for (int rt = 0; rt < 2; ++rt)
#pragma unroll
          for (int j = 0; j < 4; ++j) {
            int tl = rt * 16 + g * 4 + j;
            float val = acc[rt][ct][j] * scale;
            if (s > r0 + tl) val = -1e30f;  // causal mask
            S[tl * 264 + s] = val;
          }
      }
    }
  }
  __syncthreads();

  // ---- softmax: 8 threads/row, only needed col range ----
  {
    int row = tid >> 3, sub = tid & 7;
    const bool sact = (sub * 32) < ncol;
    float vals[32];
    float m = -3.0e38f, sum = 0.f;
    if (sact) {
#pragma unroll
      for (int i = 0; i < 32; ++i) {
        vals[i] = S[row * 264 + sub * 32 + i];
        m = fmaxf(m, vals[i]);
      }
    }
    m = fmaxf(m, __shfl_xor(m, 1));
    m = fmaxf(m, __shfl_xor(m, 2));
    m = fmaxf(m, __shfl_xor(m, 4));
    if (sact) {
#pragma unroll
      for (int i = 0; i < 32; ++i) {
        float p = __expf(vals[i] - m);
        sum += p;
        P[row * 264 + sub * 32 + i] = (_Float16)p;
      }
    }
    sum += __shfl_xor(sum, 1);
    sum += __shfl_xor(sum, 2);
    sum += __shfl_xor(sum, 4);
    if (sub == 0) lsum[row] = sum;
  }
  __syncthreads();

  // ---- PV: out[32][64] = P[32][ncol] @ v[ncol][64] ----
  f32x4 o0 = {}, o1 = {};
  const int hcol = wave * 16 + l16;
  const _Float16* vrow = &vT[(size_t)b * 16384 + (size_t)hcol * 256];
#pragma unroll
  for (int ks = 0; ks < 8; ++ks) {
    if (ks <= rb) {
      int kk = ks * 32 + g * 8;
      f16x8 a0 = *reinterpret_cast<const f16x8*>(&P[l16 * 264 + kk]);
      f16x8 a1 = *reinterpret_cast<const f16x8*>(&P[(16 + l16) * 264 + kk]);
      f16x8 bf = *reinterpret_cast<const f16x8*>(&vrow[kk]);
      o0 = MFMA16(a0, bf, o0);
      o1 = MFMA16(a1, bf, o1);
    }
  }
#pragma unroll
  for (int j = 0; j < 4; ++j) {
    int tl0 = g * 4 + j, tl1 = 16 + g * 4 + j;
    out[(rowbase + r0 + tl0) * 64 + hcol] = o0[j] / lsum[tl0];
    out[(rowbase + r0 + tl1) * 64 + hcol] = o1[j] / lsum[tl1];
  }
}

// ---------------------------------------------------------------------------
extern "C" void kernel_launch(void* const* d_in, const int* in_sizes, int n_in,
                              void* d_out, int out_size, void* d_ws, size_t ws_size,
                              hipStream_t stream) {
  const float* x  = (const float*)d_in[0];
  const float* Wq = (const float*)d_in[1];
  const float* Wk = (const float*)d_in[2];
  const float* Wv = (const float*)d_in[3];

  char* ws = (char*)d_ws;
  _Float16* wt_hi = (_Float16*)ws;                       // 192*384 f16 = 147456 B
  _Float16* wt_lo = (_Float16*)(ws + 147456);            // 147456 B
  const size_t MB16 = (size_t)131072 * 64 * 2;           // 16 MiB per f16 matrix
  char* p = ws + (1 << 20);
  _Float16* qhi = (_Float16*)(p);
  _Float16* qlo = (_Float16*)(p + MB16);
  _Float16* khi = (_Float16*)(p + 2 * MB16);
  _Float16* klo = (_Float16*)(p + 3 * MB16);
  _Float16* vT  = (_Float16*)(p + 4 * MB16);             // [512][64][256] f16

  wprep_kernel<<<288, 256, 0, stream>>>(Wq, Wk, Wv, wt_hi, wt_lo);
  qkv_gemm_kernel<<<2048, 256, 0, stream>>>(x, wt_hi, wt_lo, qhi, qlo, khi, klo, vT);
  attn_kernel<<<dim3(8, 512), 256, 0, stream>>>(qhi, qlo, khi, klo, vT, (float*)d_out);
}

// Round 3
// 158.076 us; speedup vs baseline: 1.3282x; 1.2995x over previous
//
#include <hip/hip_runtime.h>
#include <hip/hip_bf16.h>
#include <math.h>

typedef _Float16 f16x8 __attribute__((ext_vector_type(8)));
typedef _Float16 f16x4 __attribute__((ext_vector_type(4)));
typedef float f32x4 __attribute__((ext_vector_type(4)));

#define MFMA16(a, b, c) __builtin_amdgcn_mfma_f32_16x16x32_f16((a), (b), (c), 0, 0, 0)

// ---------------- kernel 0: W transpose + fp16 hi/lo split -----------------
// Wq/Wk/Wv are [384][64] row-major (C,H). Output WT[n][c], n in [0,192), c in [0,384).
__global__ __launch_bounds__(256) void wprep_kernel(
    const float* __restrict__ Wq, const float* __restrict__ Wk, const float* __restrict__ Wv,
    _Float16* __restrict__ wt_hi, _Float16* __restrict__ wt_lo) {
  int i = blockIdx.x * 256 + threadIdx.x;
  if (i >= 192 * 384) return;
  int n = i / 384, c = i - n * 384;
  int sel = n >> 6, h = n & 63;
  const float* W = (sel == 0) ? Wq : (sel == 1) ? Wk : Wv;
  float val = W[c * 64 + h];
  _Float16 hi = (_Float16)val;
  wt_hi[i] = hi;
  wt_lo[i] = (_Float16)(val - (float)hi);
}

// ---------------- fused kernel: one block per batch ------------------------
// 8 waves (512 thr). Wave w owns q-rows {16w..16w+15} U {240-16w..255-16w}.
// Phase A: qkv projection (x streamed, BK=32, 12 chunks). k hi/lo + vT -> LDS,
// q -> registers (redistributed via per-wave LDS slice).
// Phase B: causal flash attention, swapped-operand QK^T, no barriers.
__global__ __launch_bounds__(512, 2) void fused_kernel(
    const float* __restrict__ x,
    const _Float16* __restrict__ wth, const _Float16* __restrict__ wtl,
    float* __restrict__ out) {
  __shared__ __align__(16) char smem[148480];
  _Float16* xh = (_Float16*)smem;                   // [256][40] f16  (20480 B)
  _Float16* xl = (_Float16*)(smem + 20480);         // [256][40] f16
  _Float16* kh = (_Float16*)(smem + 40960);         // [256][72] f16  (36864 B)
  _Float16* kl = (_Float16*)(smem + 77824);         // [256][72] f16
  _Float16* vT = (_Float16*)(smem + 114688);        // [64][264] f16  (33792 B)

  const int tid = threadIdx.x;
  const int wave = tid >> 6, lane = tid & 63;
  const int g = lane >> 4, l16 = lane & 15;
  const int b = blockIdx.x;
  const int rset[2] = {16 * wave, 240 - 16 * wave};
  const float* xb = x + (size_t)b * 98304;  // 256*384
  _Float16* wsl = (_Float16*)smem + wave * 2304;  // per-wave slice [32][72] (4608 B)

  const float K2 = 28.270933f;  // sqrt(384) * log2(e)
  const float NINF = -__builtin_inff();

  // ---------------- Phase A: projection ----------------
  f32x4 qa[2][4] = {}, ka[2][4] = {}, va[2][4] = {};

  int srow[4], scol[4];
  float4 cur[4], nxt[4];
#pragma unroll
  for (int i = 0; i < 4; ++i) {
    int idx = tid + 512 * i;                  // 2048 float4 = 256 rows x 8
    srow[i] = idx >> 3;
    scol[i] = (idx & 7) << 2;
    cur[i] = *(const float4*)&xb[(size_t)srow[i] * 384 + scol[i]];
  }

  for (int c = 0; c < 12; ++c) {
    const int kk = c * 32;
    // stage chunk c into LDS (fp32 -> f16 hi/lo)
#pragma unroll
    for (int i = 0; i < 4; ++i) {
      float vv[4] = {cur[i].x, cur[i].y, cur[i].z, cur[i].w};
      f16x4 h4, l4;
#pragma unroll
      for (int e = 0; e < 4; ++e) {
        _Float16 h = (_Float16)vv[e];
        h4[e] = h;
        l4[e] = (_Float16)(vv[e] - (float)h);
      }
      *(f16x4*)&xh[srow[i] * 40 + scol[i]] = h4;
      *(f16x4*)&xl[srow[i] * 40 + scol[i]] = l4;
    }
    // prefetch chunk c+1 (hides HBM latency under compute below)
    if (c < 11) {
#pragma unroll
      for (int i = 0; i < 4; ++i)
        nxt[i] = *(const float4*)&xb[(size_t)srow[i] * 384 + kk + 32 + scol[i]];
    }
    __syncthreads();
    // compute: 56 MFMA per wave
#pragma unroll
    for (int s = 0; s < 2; ++s) {
      const int rs = rset[s];
      f16x8 ah = *(const f16x8*)&xh[(rs + l16) * 40 + g * 8];
      f16x8 al = *(const f16x8*)&xl[(rs + l16) * 40 + g * 8];
#pragma unroll
      for (int ct = 0; ct < 4; ++ct) {
        const size_t oq = (size_t)(ct * 16 + l16) * 384 + kk + g * 8;
        f16x8 bqh = *(const f16x8*)&wth[oq];
        f16x8 bql = *(const f16x8*)&wtl[oq];
        f16x8 bkh = *(const f16x8*)&wth[oq + 24576];  // +64*384
        f16x8 bkl = *(const f16x8*)&wtl[oq + 24576];
        f16x8 bvh = *(const f16x8*)&wth[oq + 49152];  // +128*384
        qa[s][ct] = MFMA16(ah, bqh, qa[s][ct]);
        qa[s][ct] = MFMA16(al, bqh, qa[s][ct]);
        qa[s][ct] = MFMA16(ah, bql, qa[s][ct]);
        ka[s][ct] = MFMA16(ah, bkh, ka[s][ct]);
        ka[s][ct] = MFMA16(al, bkh, ka[s][ct]);
        ka[s][ct] = MFMA16(ah, bkl, ka[s][ct]);
        va[s][ct] = MFMA16(ah, bvh, va[s][ct]);  // v: single pass
      }
    }
    __syncthreads();
    if (c < 11) {
#pragma unroll
      for (int i = 0; i < 4; ++i) cur[i] = nxt[i];
    }
  }

  // ---- epilogue: k hi/lo + vT to LDS; q set0 into per-wave slice ----
  // D layout: row = 4g+j (within 16-row tile), col = l16
#pragma unroll
  for (int s = 0; s < 2; ++s) {
    const int rs = rset[s];
#pragma unroll
    for (int ct = 0; ct < 4; ++ct) {
      const int h = ct * 16 + l16;
#pragma unroll
      for (int j = 0; j < 4; ++j) {
        const int row = rs + 4 * g + j;
        float kv = ka[s][ct][j];
        _Float16 khv = (_Float16)kv;
        kh[row * 72 + h] = khv;
        kl[row * 72 + h] = (_Float16)(kv - (float)khv);
        vT[h * 264 + row] = (_Float16)va[s][ct][j];
      }
    }
  }
  f16x8 qhf[2][2], qlf[2][2];  // [set][ks] B-fragments of q
  // set 0: write slice
#pragma unroll
  for (int ct = 0; ct < 4; ++ct) {
    const int h = ct * 16 + l16;
#pragma unroll
    for (int j = 0; j < 4; ++j) {
      const int rl = 4 * g + j;
      float qv = qa[0][ct][j];
      _Float16 qh = (_Float16)qv;
      wsl[(rl * 2 + 0) * 72 + h] = qh;
      wsl[(rl * 2 + 1) * 72 + h] = (_Float16)(qv - (float)qh);
    }
  }
  __syncthreads();  // (1) k/v + set0 slice flushed
#pragma unroll
  for (int ks = 0; ks < 2; ++ks) {
    qhf[0][ks] = *(const f16x8*)&wsl[(l16 * 2 + 0) * 72 + ks * 32 + g * 8];
    qlf[0][ks] = *(const f16x8*)&wsl[(l16 * 2 + 1) * 72 + ks * 32 + g * 8];
  }
  __syncthreads();  // (2) set0 reads done before overwrite
#pragma unroll
  for (int ct = 0; ct < 4; ++ct) {
    const int h = ct * 16 + l16;
#pragma unroll
    for (int j = 0; j < 4; ++j) {
      const int rl = 4 * g + j;
      float qv = qa[1][ct][j];
      _Float16 qh = (_Float16)qv;
      wsl[(rl * 2 + 0) * 72 + h] = qh;
      wsl[(rl * 2 + 1) * 72 + h] = (_Float16)(qv - (float)qh);
    }
  }
  __syncthreads();  // (3) set1 slice flushed
#pragma unroll
  for (int ks = 0; ks < 2; ++ks) {
    qhf[1][ks] = *(const f16x8*)&wsl[(l16 * 2 + 0) * 72 + ks * 32 + g * 8];
    qlf[1][ks] = *(const f16x8*)&wsl[(l16 * 2 + 1) * 72 + ks * 32 + g * 8];
  }

  // ---------------- Phase B: causal flash attention (no barriers) ----------
  _Float16* psl = wsl;  // per-wave P slice [32][72]
  float mrun[2] = {NINF, NINF}, srun[2] = {0.f, 0.f};
  f32x4 O[2][4] = {};

  for (int c = 0; c < 4; ++c) {
    const int kb = c * 64;
#pragma unroll
    for (int s = 0; s < 2; ++s) {
      const int rs = rset[s];
      if (kb > rs + 15) continue;  // set inactive for this K-chunk (wave-uniform)
      const int qr = rs + l16;     // this lane's q-row (fixed)
      // QK^T swapped: sa[kt][j] = S[qr][kb+16kt+4g+j]
      f32x4 sa[4] = {};
#pragma unroll
      for (int kt = 0; kt < 4; ++kt) {
        if (kb + 16 * kt > rs + 15) continue;  // fully-masked tile (wave-uniform)
#pragma unroll
        for (int ks = 0; ks < 2; ++ks) {
          const int ko = (kb + 16 * kt + l16) * 72 + ks * 32 + g * 8;
          f16x8 akh = *(const f16x8*)&kh[ko];
          f16x8 akl = *(const f16x8*)&kl[ko];
          sa[kt] = MFMA16(akh, qhf[s][ks], sa[kt]);
          sa[kt] = MFMA16(akl, qhf[s][ks], sa[kt]);
          sa[kt] = MFMA16(akh, qlf[s][ks], sa[kt]);
        }
      }
      // causal mask + chunk max
      float cm = NINF;
#pragma unroll
      for (int kt = 0; kt < 4; ++kt)
#pragma unroll
        for (int j = 0; j < 4; ++j) {
          const int krow = kb + 16 * kt + 4 * g + j;
          float sv = (krow <= qr) ? sa[kt][j] : NINF;
          sa[kt][j] = sv;
          cm = fmaxf(cm, sv);
        }
      cm = fmaxf(cm, __shfl_xor(cm, 16));
      cm = fmaxf(cm, __shfl_xor(cm, 32));
      const float mn = fmaxf(mrun[s], cm);
      const float scl = exp2f(K2 * (mrun[s] - mn));  // 0 on first chunk
      mrun[s] = mn;
      // P = exp(scale*(S-m)) -> f16 slice; sum
      float cs = 0.f;
#pragma unroll
      for (int kt = 0; kt < 4; ++kt)
#pragma unroll
        for (int j = 0; j < 4; ++j) {
          float p = exp2f(K2 * (sa[kt][j] - mn));
          cs += p;
          psl[(s * 16 + l16) * 72 + kt * 16 + 4 * g + j] = (_Float16)p;
        }
      cs += __shfl_xor(cs, 16);
      cs += __shfl_xor(cs, 32);
      srun[s] = srun[s] * scl + cs;
#pragma unroll
      for (int ht = 0; ht < 4; ++ht) O[s][ht] *= scl;
      // make P writes visible to this wave's reads, defeat MFMA hoisting
      asm volatile("s_waitcnt lgkmcnt(0)" ::: "memory");
      __builtin_amdgcn_sched_barrier(0);
      // PV: O^T[h][qr] += v^T[h][s] * P^T[s][qr]
#pragma unroll
      for (int ks2 = 0; ks2 < 2; ++ks2) {
        f16x8 bp = *(const f16x8*)&psl[(s * 16 + l16) * 72 + ks2 * 32 + g * 8];
#pragma unroll
        for (int ht = 0; ht < 4; ++ht) {
          f16x8 av = *(const f16x8*)&vT[(ht * 16 + l16) * 264 + kb + ks2 * 32 + g * 8];
          O[s][ht] = MFMA16(av, bp, O[s][ht]);
        }
      }
    }
  }

  // ---- output: out[qr][h] = O^T[h][qr] / srun ----
#pragma unroll
  for (int s = 0; s < 2; ++s) {
    const int qr = rset[s] + l16;
    const float inv = 1.0f / srun[s];
#pragma unroll
    for (int ht = 0; ht < 4; ++ht) {
      f32x4 r = O[s][ht] * inv;
      *(f32x4*)&out[((size_t)b * 256 + qr) * 64 + ht * 16 + 4 * g] = r;
    }
  }
}

// ---------------------------------------------------------------------------
extern "C" void kernel_launch(void* const* d_in, const int* in_sizes, int n_in,
                              void* d_out, int out_size, void* d_ws, size_t ws_size,
                              hipStream_t stream) {
  const float* x  = (const float*)d_in[0];
  const float* Wq = (const float*)d_in[1];
  const float* Wk = (const float*)d_in[2];
  const float* Wv = (const float*)d_in[3];

  char* ws = (char*)d_ws;
  _Float16* wt_hi = (_Float16*)ws;             // 192*384 f16 = 147456 B
  _Float16* wt_lo = (_Float16*)(ws + 147456);  // 147456 B

  wprep_kernel<<<288, 256, 0, stream>>>(Wq, Wk, Wv, wt_hi, wt_lo);
  fused_kernel<<<512, 512, 0, stream>>>(x, wt_hi, wt_lo, (float*)d_out);
}